// Round 8
// baseline (390.011 us; speedup 1.0000x reference)
//
#include <hip/hip_runtime.h>

// Problem constants
#define NTOK 65536          // B*S tokens
#define DDIM 64             // embedding dim
#define KCB  4096           // codebook size
#define MB   128            // tokens per block
#define NCH  128            // codes per staged chunk
#define NCHUNKS (KCB / NCH) // 32
#define ESTR 72             // padded LDS row stride (bf16 elems); 144B rows, 16B-aligned
#define LCAP 6144           // candidate capacity (expect ~1-2K with lagged threshold)
#define WWIN 4.0e-5f        // >= 2*(ulp(s<256) + 3-product split err ~2e-7)
#define IDXOFF  (NTOK * DDIM)
#define LOSSOFF (NTOK * DDIM + NTOK)

typedef __bf16 bf16x8 __attribute__((ext_vector_type(8)));
typedef float  f32x4  __attribute__((ext_vector_type(4)));

__device__ __forceinline__ float opaque(float x) { asm volatile("" : "+v"(x)); return x; }

// numpy pairwise sum of squares, n=64
__device__ __forceinline__ float np_sumsq64(const float* __restrict__ v) {
    float r[8];
#pragma unroll
    for (int j = 0; j < 8; ++j) r[j] = opaque(v[j] * v[j]);
#pragma unroll
    for (int i = 1; i < 8; ++i)
#pragma unroll
        for (int j = 0; j < 8; ++j) r[j] += opaque(v[8 * i + j] * v[8 * i + j]);
    return ((r[0] + r[1]) + (r[2] + r[3])) + ((r[4] + r[5]) + (r[6] + r[7]));
}

__device__ __forceinline__ unsigned short bf16rne(float x) {
    unsigned u = __float_as_uint(x);
    return (unsigned short)((u + 0x7fffu + ((u >> 16) & 1u)) >> 16);
}
__device__ __forceinline__ float bf16tof(unsigned short h) {
    return __uint_as_float(((unsigned)h) << 16);
}

// ---- Prep: e2 (np pairwise) + split-bf16 codebook + zero loss ----
__global__ void k_prep(const float* __restrict__ emb, float* __restrict__ e2,
                       unsigned short* __restrict__ eh, unsigned short* __restrict__ el,
                       double* __restrict__ lossacc) {
    int k = blockIdx.x * blockDim.x + threadIdx.x;
    if (k == 0) *lossacc = 0.0;
    if (k >= KCB) return;
    float row[DDIM];
    const float4* r4 = (const float4*)(emb + (size_t)k * DDIM);
#pragma unroll
    for (int i = 0; i < DDIM / 4; ++i) {
        float4 v = r4[i];
        row[4*i+0] = v.x; row[4*i+1] = v.y; row[4*i+2] = v.z; row[4*i+3] = v.w;
    }
    e2[k] = np_sumsq64(row);
#pragma unroll
    for (int j = 0; j < DDIM; ++j) {
        unsigned short h = bf16rne(row[j]);
        unsigned short l = bf16rne(row[j] - bf16tof(h));
        eh[(size_t)k * DDIM + j] = h;
        el[(size_t)k * DDIM + j] = l;
    }
}

// ---- Main: SINGLE MFMA sweep (lagged-threshold candidate capture) + exact rescore ----
// 512 thr = 8 waves; wm = w>>2 (0..1): 64-token group (ms 0..3); wn = w&3: 32-col group.
// m~ = (2z)@e^T via 3 bf16-split MFMA products; shat = fl(fl(z2+e2)-m~).
// Preview pass seeds v0 (chunk-0 min) before any appends; appends use
// threshold min(lane-run, lagged v0)+W  (both >= final min => superset captured).
// Exact np-chain rescore of candidates -> lexicographic (s,n) = np argmin.
__global__ __launch_bounds__(512, 2)
void k_vq(const float* __restrict__ z, const float* __restrict__ emb,
          const float* __restrict__ e2g,
          const unsigned short* __restrict__ ehg, const unsigned short* __restrict__ elg,
          float* __restrict__ out, double* __restrict__ lossacc) {
    __shared__ alignas(16) unsigned short esh[2][NCH * ESTR];  // 36 KB (dbuf)
    __shared__ alignas(16) unsigned short esl[2][NCH * ESTR];  // 36 KB
    __shared__ float e2t[2][NCH];
    __shared__ float z2s[MB];
    __shared__ unsigned v0u[MB];
    __shared__ unsigned long long keys[MB];
    __shared__ unsigned list[LCAP];          // 24 KB
    __shared__ int lcnt;
    __shared__ float red[512];
    __shared__ int bidx_s[MB];

    const int tid  = threadIdx.x;
    const int lane = tid & 63;
    const int l15  = lane & 15;
    const int quad = lane >> 4;
    const int w    = tid >> 6;
    const int wm   = w >> 2;    // 0..1 : 64-token group
    const int wn   = w & 3;     // 0..3 : 32-col group
    const int tok0 = blockIdx.x * MB;
    const size_t zbase = (size_t)tok0 * DDIM;

    if (tid < MB) { v0u[tid] = 0x7f800000u; keys[tid] = 0xFFFFFFFFFFFFFFFFull; }
    if (tid == 0) lcnt = 0;

    // ---- A-fragments (2*z, split bf16) from global into VGPRs (whole-kernel live) ----
    bf16x8 Ah[4][2], Al[4][2];   // [ms][kh]
#pragma unroll
    for (int ms = 0; ms < 4; ++ms) {
        const float* p = z + zbase + (size_t)(wm * 64 + ms * 16 + l15) * DDIM + quad * 8;
#pragma unroll
        for (int kh = 0; kh < 2; ++kh) {
            float4 u0 = *(const float4*)(p + kh * 32);
            float4 u1 = *(const float4*)(p + kh * 32 + 4);
            float d[8] = {u0.x + u0.x, u0.y + u0.y, u0.z + u0.z, u0.w + u0.w,
                          u1.x + u1.x, u1.y + u1.y, u1.z + u1.z, u1.w + u1.w};
            union { bf16x8 v; unsigned short u[8]; } th, tl;
#pragma unroll
            for (int j = 0; j < 8; ++j) {
                unsigned short h = bf16rne(d[j]);
                th.u[j] = h;
                tl.u[j] = bf16rne(d[j] - bf16tof(h));
            }
            Ah[ms][kh] = th.v;
            Al[ms][kh] = tl.v;
        }
    }

    // z2 per token: exact np pairwise
    if (tid < MB) {
        float row[DDIM];
        const float4* zr4 = (const float4*)(z + zbase + (size_t)tid * DDIM);
#pragma unroll
        for (int i = 0; i < DDIM / 4; ++i) {
            float4 v = zr4[i];
            row[4*i+0] = v.x; row[4*i+1] = v.y; row[4*i+2] = v.z; row[4*i+3] = v.w;
        }
        z2s[tid] = np_sumsq64(row);
    }

    // ---- stage chunk 0 into buffer 0 ----
#pragma unroll
    for (int it = 0; it < 4; ++it) {
        int f = it * 512 + tid, rr = f >> 4, c4 = f & 15;
        *(ushort4*)(&esh[0][rr * ESTR + c4 * 4]) =
            ((const ushort4*)(ehg + (size_t)rr * DDIM))[c4];
        *(ushort4*)(&esl[0][rr * ESTR + c4 * 4]) =
            ((const ushort4*)(elg + (size_t)rr * DDIM))[c4];
    }
    if (tid < NCH) e2t[0][tid] = e2g[tid];
    __syncthreads();

    f32x4 z2l[4];
#pragma unroll
    for (int ms = 0; ms < 4; ++ms)
        z2l[ms] = *(const f32x4*)(z2s + wm * 64 + ms * 16 + quad * 4);

    float vrun[16], vl[16];
#pragma unroll
    for (int i = 0; i < 16; ++i) { vrun[i] = 3.0e38f; vl[i] = 3.0e38f; }

    auto mfma_chunk = [&](int buf, int n0, bool append) {
#pragma unroll
        for (int ns2 = 0; ns2 < 2; ++ns2) {
            int nl = wn * 32 + ns2 * 16 + l15;
            const unsigned short* pb = &esh[buf][nl * ESTR + quad * 8];
            const unsigned short* pc = &esl[buf][nl * ESTR + quad * 8];
            bf16x8 Bh0 = *(const bf16x8*)pb;
            bf16x8 Bh1 = *(const bf16x8*)(pb + 32);
            bf16x8 Bl0 = *(const bf16x8*)pc;
            bf16x8 Bl1 = *(const bf16x8*)(pc + 32);
            float e2v = e2t[buf][nl];
            int   n   = n0 + nl;
#pragma unroll
            for (int ms = 0; ms < 4; ++ms) {
                f32x4 a0 = {0.f, 0.f, 0.f, 0.f}, a1 = {0.f, 0.f, 0.f, 0.f};
                a0 = __builtin_amdgcn_mfma_f32_16x16x32_bf16(Ah[ms][0], Bh0, a0, 0, 0, 0);
                a1 = __builtin_amdgcn_mfma_f32_16x16x32_bf16(Ah[ms][1], Bh1, a1, 0, 0, 0);
                a0 = __builtin_amdgcn_mfma_f32_16x16x32_bf16(Ah[ms][0], Bl0, a0, 0, 0, 0);
                a1 = __builtin_amdgcn_mfma_f32_16x16x32_bf16(Ah[ms][1], Bl1, a1, 0, 0, 0);
                a0 = __builtin_amdgcn_mfma_f32_16x16x32_bf16(Al[ms][0], Bh0, a0, 0, 0, 0);
                a1 = __builtin_amdgcn_mfma_f32_16x16x32_bf16(Al[ms][1], Bh1, a1, 0, 0, 0);
#pragma unroll
                for (int r = 0; r < 4; ++r) {
                    int i = ms * 4 + r;
                    float shat = (z2l[ms][r] + e2v) - (a0[r] + a1[r]);
                    if (append && shat <= fminf(vrun[i], vl[i]) + WWIN) {
                        int m = wm * 64 + ms * 16 + quad * 4 + r;
                        int idx = atomicAdd(&lcnt, 1);
                        if (idx < LCAP) list[idx] = ((unsigned)m << 12) | (unsigned)n;
                    }
                    vrun[i] = fminf(vrun[i], shat);
                }
            }
        }
    };
    auto v0_commit = [&]() {
#pragma unroll
        for (int vi = 0; vi < 16; ++vi) {
            float v = vrun[vi];
            v = fminf(v, __shfl_xor(v, 1));
            v = fminf(v, __shfl_xor(v, 2));
            v = fminf(v, __shfl_xor(v, 4));
            v = fminf(v, __shfl_xor(v, 8));
            if (l15 == 0)
                atomicMin(&v0u[wm*64 + (vi>>2)*16 + quad*4 + (vi&3)], __float_as_uint(v));
        }
    };
    auto vl_reload = [&]() {
#pragma unroll
        for (int vi = 0; vi < 16; ++vi)
            vl[vi] = __uint_as_float(v0u[wm*64 + (vi>>2)*16 + quad*4 + (vi&3)]);
    };

    // ---- preview: chunk 0, no appends -> seeds v0 ----
    mfma_chunk(0, 0, false);
    v0_commit();
    __syncthreads();
    vl_reload();

    // ---- main sweep: dbuf staging, one barrier/chunk ----
#pragma unroll 1
    for (int c = 0; c < NCHUNKS; ++c) {
        ushort4 peh[4], pel[4];
        float e2p = 0.f;
        if (c + 1 < NCHUNKS) {
            const int nb = (c + 1) * NCH;
#pragma unroll
            for (int it = 0; it < 4; ++it) {
                int f = it * 512 + tid, rr = f >> 4, c4 = f & 15;
                peh[it] = ((const ushort4*)(ehg + (size_t)(nb + rr) * DDIM))[c4];
                pel[it] = ((const ushort4*)(elg + (size_t)(nb + rr) * DDIM))[c4];
            }
            if (tid < NCH) e2p = e2g[nb + tid];
        }
        mfma_chunk(c & 1, c * NCH, true);
        if (c + 1 < NCHUNKS) {
            const int nbuf = (c + 1) & 1;
#pragma unroll
            for (int it = 0; it < 4; ++it) {
                int f = it * 512 + tid, rr = f >> 4, c4 = f & 15;
                *(ushort4*)(&esh[nbuf][rr * ESTR + c4 * 4]) = peh[it];
                *(ushort4*)(&esl[nbuf][rr * ESTR + c4 * 4]) = pel[it];
            }
            if (tid < NCH) e2t[nbuf][tid] = e2p;
        }
        if (c & 1) v0_commit();
        __syncthreads();
        if (c & 1) vl_reload();
    }

    // ---- Exact rescore (np chain), lexicographic (s, n) min per token ----
    int cnt = lcnt; if (cnt > LCAP) cnt = LCAP;
    for (int i = tid; i < cnt; i += 512) {
        unsigned e = list[i];
        int m = (int)(e >> 12), n = (int)(e & 4095u);
        const float* zrow = z + zbase + (size_t)m * DDIM;
        const float* erow = emb + (size_t)n * DDIM;
        float a = 0.f;
#pragma unroll
        for (int j = 0; j < DDIM; ++j) a = fmaf(zrow[j] + zrow[j], erow[j], a);
        float s = (z2s[m] + e2g[n]) - a;   // two fp32 roundings, exactly as np
        unsigned long long key = ((unsigned long long)__float_as_uint(s) << 32)
                               | (unsigned long long)(unsigned)n;
        atomicMin(&keys[m], key);
    }
    __syncthreads();

    if (tid < MB) {
        int nstar = (int)(keys[tid] & 0xffffffffULL);
        bidx_s[tid] = nstar;
        out[IDXOFF + tok0 + tid] = (float)nstar;
    }
    __syncthreads();

    // ---- Epilogue: quantized gather-write (coalesced float4) + loss ----
    float lsum = 0.f;
#pragma unroll
    for (int it = 0; it < 4; ++it) {
        int f  = it * 512 + tid;    // 0..2047 float4 slots
        int tt = f >> 4, cc = f & 15;
        int idx = bidx_s[tt];
        float4 qv = ((const float4*)(emb + (size_t)idx * DDIM))[cc];
        float4 zv = ((const float4*)(z + zbase))[f];
        ((float4*)(out + zbase))[f] = qv;
        float dx = qv.x - zv.x, dy = qv.y - zv.y;
        float dz = qv.z - zv.z, dw = qv.w - zv.w;
        lsum += dx * dx + dy * dy + dz * dz + dw * dw;
    }
    red[tid] = lsum;
    __syncthreads();
    for (int s = 256; s > 0; s >>= 1) {
        if (tid < s) red[tid] += red[tid + s];
        __syncthreads();
    }
    if (tid == 0) atomicAdd(lossacc, (double)red[0]);
}

__global__ void k_fin(const double* __restrict__ lossacc, float* __restrict__ out) {
    out[LOSSOFF] = (float)(2.0 * (*lossacc) / (double)(NTOK * DDIM));
}

extern "C" void kernel_launch(void* const* d_in, const int* in_sizes, int n_in,
                              void* d_out, int out_size, void* d_ws, size_t ws_size,
                              hipStream_t stream) {
    const float* z   = (const float*)d_in[0];   // [16,4096,64] fp32
    const float* emb = (const float*)d_in[1];   // [4096,64] fp32
    float* out = (float*)d_out;

    char* ws = (char*)d_ws;
    float*          e2g     = (float*)(ws);                    // 16 KB
    unsigned short* ehg     = (unsigned short*)(ws + 16384);   // 512 KB
    unsigned short* elg     = (unsigned short*)(ws + 540672);  // 512 KB
    double*         lossacc = (double*)(ws + 1064960);

    hipLaunchKernelGGL(k_prep, dim3(16), dim3(256), 0, stream, emb, e2g, ehg, elg, lossacc);
    hipLaunchKernelGGL(k_vq, dim3(NTOK / MB), dim3(512), 0, stream,
                       z, emb, e2g, ehg, elg, out, lossacc);
    hipLaunchKernelGGL(k_fin, dim3(1), dim3(1), 0, stream, lossacc, out);
}